// Round 6
// baseline (294.815 us; speedup 1.0000x reference)
//
#include <hip/hip_runtime.h>
#include <hip/hip_bf16.h>

// GCNConv + ReLU: out = relu( (A_norm @ (x W)) + b ), A_norm = D^-1/2 (A + I) D^-1/2
// Round 12: aggregate v3. Evidence from rounds 2/4/5: time tracks distinct
// 64B-line requests (~0.5-1 line/cyc/CU), not bytes (190 MB misses was no
// faster than 352 MB). Changes: (1) self-phased slice-OUTER-LOOP in one
// fully-co-resident 782-block grid (phase coherence from loop order, fixing
// the packing-vs-slice-exclusivity conflict that pushed FETCH 132->190 MB);
// (2) uint4 gathers, wave = 16 nodes x 4 col-lanes (4 lanes/line, half the
// gather instrs, 16-deep pipeline = ~192 lines in flight/CU); (3) LDS-cached
// edge indices (64/node, sentinel-padded, rare global fallback) -- kills the
// scattered global idx loads that were ~half of round-5's line requests.

#define FEATS 256
#define MAXBUCK 200   // >= (50000+255)>>8 = 196
#define P1_CAP 64     // LDS slots per bucket per 4096-edge chunk (mean ~21)
#define BCAP 10240    // temp capacity per bucket (mean 8192, ~22 sigma)
#define AGG_CAP 64    // cached indices per node
#define AGG_STR 72    // ushort stride (144 B, 16B-aligned) to dodge bank conflicts

typedef __bf16 bf16x8 __attribute__((ext_vector_type(8)));
typedef float f32x4 __attribute__((ext_vector_type(4)));

__device__ __forceinline__ unsigned short f2bf(float f) {  // RNE
  unsigned u = __float_as_uint(f);
  u += 0x7fffu + ((u >> 16) & 1u);
  return (unsigned short)(u >> 16);
}
__device__ __forceinline__ float bflo(unsigned u) { return __uint_as_float(u << 16); }
__device__ __forceinline__ float bfhi(unsigned u) { return __uint_as_float(u & 0xFFFF0000u); }

// ---------------- init: zero bucket cursors + zero sentinel rows of xwp ----------------

__global__ __launch_bounds__(512) void init_misc(int* __restrict__ gcursor, int nbuck,
                                                 int* __restrict__ xwp_i, int npad, int n) {
  const int t = threadIdx.x;
  if (t < nbuck) gcursor[t] = 0;
  const int j = t - 256;           // 128 ints = 8 slices x 64 B sentinel rows
  if (j >= 0 && j < 128) {
    const int s = j >> 4, w = j & 15;
    xwp_i[((size_t)s * npad + n) * 16 + w] = 0;
  }
}

// ---------------- CSR build ----------------

// pass1: bin packed edges (dst<<16|src) by dst>>8. 1024 threads, 4096 edges/block.
__global__ __launch_bounds__(1024) void pass1_bin(const int* __restrict__ src,
                                                  const int* __restrict__ dst,
                                                  int E, int nbuck,
                                                  int* __restrict__ gcursor,
                                                  unsigned* __restrict__ temp) {
  __shared__ unsigned lbuf[MAXBUCK * P1_CAP];  // 51.2 KB
  __shared__ int lcnt[MAXBUCK];
  __shared__ int lbase[MAXBUCK];
  const int tid = threadIdx.x;
  for (int i = tid; i < nbuck; i += 1024) lcnt[i] = 0;
  __syncthreads();

  const int e0 = blockIdx.x * 4096;
  #pragma unroll
  for (int i = 0; i < 4; ++i) {
    int e = e0 + i * 1024 + tid;
    if (e < E) {
      unsigned d = (unsigned)dst[e];
      unsigned p = (d << 16) | (unsigned)src[e];
      int b = (int)(d >> 8);
      int pos = atomicAdd(&lcnt[b], 1);
      if (pos < P1_CAP) {
        lbuf[b * P1_CAP + pos] = p;
      } else {  // rare spill: direct global scatter
        int gp = atomicAdd(&gcursor[b], 1);
        temp[(size_t)b * BCAP + gp] = p;
      }
    }
  }
  __syncthreads();
  if (tid < nbuck) {
    int c = lcnt[tid]; if (c > P1_CAP) c = P1_CAP;
    lcnt[tid] = c;
    lbase[tid] = atomicAdd(&gcursor[tid], c);
  }
  __syncthreads();
  for (int i = tid; i < nbuck * P1_CAP; i += 1024) {
    int b = i >> 6, j = i & (P1_CAP - 1);
    if (j < lcnt[b]) temp[(size_t)b * BCAP + lbase[b] + j] = lbuf[i];
  }
}

// exclusive scan over bucket counts (nbuck <= 256), one block
__global__ __launch_bounds__(256) void scan_buckets(const int* __restrict__ gcursor,
                                                    int* __restrict__ bbase,
                                                    int* __restrict__ row_ptr,
                                                    int nbuck, int n) {
  __shared__ int tmp[256];
  int t = threadIdx.x;
  int v = (t < nbuck) ? min(gcursor[t], BCAP) : 0;
  tmp[t] = v;
  __syncthreads();
  #pragma unroll
  for (int off = 1; off < 256; off <<= 1) {
    int x = (t >= off) ? tmp[t - off] : 0;
    __syncthreads();
    tmp[t] += x;
    __syncthreads();
  }
  if (t < nbuck) bbase[t] = tmp[t] - v;
  if (t == 0) row_ptr[n] = tmp[255];
}

// pass2: per-bucket local CSR. 1024 threads.
__global__ __launch_bounds__(1024) void pass2_csr(const unsigned* __restrict__ temp,
                                                  const int* __restrict__ gcursor,
                                                  const int* __restrict__ bbase,
                                                  unsigned short* __restrict__ csr16,
                                                  int* __restrict__ row_ptr,
                                                  float* __restrict__ dinv, int n) {
  __shared__ unsigned ebuf[BCAP];          // 40 KB
  __shared__ unsigned short sorted[BCAP];  // 20 KB
  __shared__ int hist[256], scn[256], sexcl[256], ofs[256];
  const int b = blockIdx.x;
  const int tid = threadIdx.x;
  int cnt = gcursor[b]; if (cnt > BCAP) cnt = BCAP;
  const int base = bbase[b];
  const unsigned* tp = temp + (size_t)b * BCAP;

  if (tid < 256) { hist[tid] = 0; ofs[tid] = 0; }
  for (int i = tid; i < cnt; i += 1024) ebuf[i] = tp[i];
  __syncthreads();
  for (int i = tid; i < cnt; i += 1024) atomicAdd(&hist[(ebuf[i] >> 16) & 255], 1);
  __syncthreads();

  if (tid < 256) scn[tid] = hist[tid];
  __syncthreads();
  #pragma unroll
  for (int off = 1; off < 256; off <<= 1) {
    int x = 0;
    if (tid < 256 && tid >= off) x = scn[tid - off];
    __syncthreads();
    if (tid < 256) scn[tid] += x;
    __syncthreads();
  }
  if (tid < 256) {
    int v = hist[tid];
    int excl = scn[tid] - v;
    sexcl[tid] = excl;
    int node = (b << 8) + tid;
    if (node < n) {
      row_ptr[node] = base + excl;
      dinv[node] = rsqrtf((float)(v + 1));  // +1 self loop
    }
  }
  __syncthreads();

  for (int i = tid; i < cnt; i += 1024) {
    unsigned e = ebuf[i];
    int dl = (int)((e >> 16) & 255);
    int pos = sexcl[dl] + atomicAdd(&ofs[dl], 1);
    sorted[pos] = (unsigned short)(e & 0xFFFFu);
  }
  __syncthreads();
  for (int i = tid; i < cnt; i += 1024) csr16[base + i] = sorted[i];
}

// ---------------- W transpose + bf16 convert: Wt[n][k] = bf16(W[k][n]) ----------------

__global__ __launch_bounds__(256) void wt_build(const float* __restrict__ W,
                                                unsigned short* __restrict__ Wt) {
  int k = blockIdx.x;
  int nn = threadIdx.x;
  Wt[nn * FEATS + k] = f2bf(W[k * FEATS + nn]);
}

// ---------------- MFMA GEMM (round-8 structure), slice-major epilogue ----------------

__global__ __launch_bounds__(256, 2) void gemm_mfma(const float* __restrict__ x,
                                                    const unsigned short* __restrict__ Wt,
                                                    const float* __restrict__ dinv,
                                                    unsigned short* __restrict__ xwp,
                                                    int M, int npad) {
  __shared__ bf16x8 A_lds[32 * 64];  // [sub*8+kc][lane], 32 KB
  const int wv   = (int)(threadIdx.x >> 6);  // wave id = col-group = conversion sub
  const int lane = (int)(threadIdx.x & 63);
  const int lm   = lane & 15;
  const int quad = lane >> 4;
  const int m0   = (int)blockIdx.x * 64;

  // B panel: loaded once, lives in registers for the whole block
  bf16x8 Bfrag[4][8];
  #pragma unroll
  for (int ct = 0; ct < 4; ++ct) {
    const unsigned short* wrow = Wt + (size_t)(wv * 64 + ct * 16 + lm) * FEATS + quad * 8;
    #pragma unroll
    for (int kc = 0; kc < 8; ++kc)
      Bfrag[ct][kc] = *(const bf16x8*)(wrow + kc * 32);
  }

  // stage A sub = wv
  {
    int arow = m0 + wv * 16 + lm; if (arow >= M) arow = M - 1;
    const float* xrow = x + (size_t)arow * FEATS + quad * 8;
    #pragma unroll
    for (int kc = 0; kc < 8; ++kc) {
      const float4 f0 = *(const float4*)(xrow + kc * 32);
      const float4 f1 = *(const float4*)(xrow + kc * 32 + 4);
      union { bf16x8 v; unsigned short u[8]; } a;
      a.u[0] = f2bf(f0.x); a.u[1] = f2bf(f0.y); a.u[2] = f2bf(f0.z); a.u[3] = f2bf(f0.w);
      a.u[4] = f2bf(f1.x); a.u[5] = f2bf(f1.y); a.u[6] = f2bf(f1.z); a.u[7] = f2bf(f1.w);
      A_lds[(wv * 8 + kc) * 64 + lane] = a.v;
    }
  }
  __syncthreads();

  // compute: 4 row-subs x (8 kc x 4 ct) MFMAs, A from LDS, B from registers
  #pragma unroll
  for (int sub = 0; sub < 4; ++sub) {
    bf16x8 Af[8];
    #pragma unroll
    for (int kc = 0; kc < 8; ++kc) Af[kc] = A_lds[(sub * 8 + kc) * 64 + lane];

    f32x4 acc[4];
    #pragma unroll
    for (int ct = 0; ct < 4; ++ct) acc[ct] = (f32x4){0.f, 0.f, 0.f, 0.f};

    #pragma unroll
    for (int kc = 0; kc < 8; ++kc) {
      #pragma unroll
      for (int ct = 0; ct < 4; ++ct)
        acc[ct] = __builtin_amdgcn_mfma_f32_16x16x32_bf16(Af[kc], Bfrag[ct][kc], acc[ct], 0, 0, 0);
    }

    #pragma unroll
    for (int r = 0; r < 4; ++r) {
      const int row = m0 + sub * 16 + quad * 4 + r;
      if (row < M) {
        const float dd = dinv[row];
        #pragma unroll
        for (int ct = 0; ct < 4; ++ct) {
          const int c = wv * 64 + ct * 16 + lm;
          const int sl = c >> 5, off = c & 31;  // slice-major write
          xwp[((size_t)sl * npad + row) * 32 + off] = f2bf(acc[ct][r] * dd);
        }
      }
    }
  }
}

// ---------------- aggregation v3: self-phased slice loop, uint4 gathers ----------------
// Grid 782 blocks (fully co-resident). Wave = 16 nodes (eg) x 4 col-lanes (cl,
// 16 B each => 4 lanes per 64 B row). Block loops slices 0..7; all blocks are
// resident so slice phases stay loosely aligned => per-slice L2 residency.
// Edge indices cached in LDS once (64/node, sentinel n beyond degree), read
// back as ds_read_b128 broadcasts -- no scattered global idx loads.

__global__ __launch_bounds__(256) void aggregate(const unsigned short* __restrict__ xwp,
                                                 const float* __restrict__ dinv,
                                                 const int* __restrict__ row_ptr,
                                                 const unsigned short* __restrict__ csr16,
                                                 const float* __restrict__ bias,
                                                 float* __restrict__ out,
                                                 int n, int npad) {
  __shared__ __align__(16) unsigned short idx_lds[64 * AGG_STR];  // 9216 B
  const int wv   = (int)(threadIdx.x >> 6);
  const int lane = (int)(threadIdx.x & 63);
  const int eg   = lane >> 2;   // node within wave
  const int cl   = lane & 3;    // 16B column group within 64B slice row
  const int nb0  = (int)blockIdx.x * 64;
  const int node = nb0 + wv * 16 + eg;
  const bool valid = node < n;
  const int nodec = valid ? node : n;  // sentinel row for invalid

  // fill this wave's 16 index rows (sentinel-padded); wave-private => no barrier
  #pragma unroll 1
  for (int ln = 0; ln < 16; ++ln) {
    const int nd = nb0 + wv * 16 + ln;
    unsigned short v = (unsigned short)n;
    if (nd < n) {
      const int b0 = row_ptr[nd];
      const int d  = row_ptr[nd + 1] - b0;
      if (lane < d) v = csr16[b0 + lane];  // lane < 64 == AGG_CAP
    }
    idx_lds[(wv * 16 + ln) * AGG_STR + lane] = v;
  }

  const int beg = valid ? row_ptr[node] : 0;
  const int deg = valid ? row_ptr[node + 1] - beg : 0;
  int mdeg = deg;  // wave-max degree (cl lanes share value; fold eg dim)
  #pragma unroll
  for (int st = 4; st < 64; st <<= 1) mdeg = max(mdeg, __shfl_xor(mdeg, st));
  const int lim = min(mdeg, AGG_CAP);

  const float dd = valid ? dinv[node] : 0.f;
  const uint4* lq = (const uint4*)(idx_lds + (wv * 16 + eg) * AGG_STR);

  for (int sl = 0; sl < 8; ++sl) {
    const unsigned short* xs = xwp + (size_t)sl * npad * 32 + cl * 8;
    // self-loop row
    uint4 v = *(const uint4*)(xs + ((size_t)nodec << 5));
    float a0 = bflo(v.x), a1 = bfhi(v.x), a2 = bflo(v.y), a3 = bfhi(v.y);
    float a4 = bflo(v.z), a5 = bfhi(v.z), a6 = bflo(v.w), a7 = bfhi(v.w);

    for (int j0 = 0; j0 < lim; j0 += 16) {  // 16 gathers in flight
      const uint4 q0 = lq[(j0 >> 3)];
      const uint4 q1 = lq[(j0 >> 3) + 1];
      const unsigned qq[8] = {q0.x, q0.y, q0.z, q0.w, q1.x, q1.y, q1.z, q1.w};
      uint4 vv[16];
      #pragma unroll
      for (int k = 0; k < 8; ++k) {
        vv[2 * k]     = *(const uint4*)(xs + ((size_t)(qq[k] & 0xFFFFu) << 5));
        vv[2 * k + 1] = *(const uint4*)(xs + ((size_t)(qq[k] >> 16) << 5));
      }
      #pragma unroll
      for (int k = 0; k < 16; ++k) {
        a0 += bflo(vv[k].x); a1 += bfhi(vv[k].x);
        a2 += bflo(vv[k].y); a3 += bfhi(vv[k].y);
        a4 += bflo(vv[k].z); a5 += bfhi(vv[k].z);
        a6 += bflo(vv[k].w); a7 += bfhi(vv[k].w);
      }
    }
    if (mdeg > AGG_CAP) {  // rare: degree beyond cache, global idx fallback
      for (int j0 = AGG_CAP; j0 < mdeg; j0 += 8) {
        int sj[8]; uint4 vv[8];
        #pragma unroll
        for (int k = 0; k < 8; ++k) {
          const int j = j0 + k;
          sj[k] = (j < deg) ? (int)csr16[beg + j] : n;
        }
        #pragma unroll
        for (int k = 0; k < 8; ++k) vv[k] = *(const uint4*)(xs + ((size_t)sj[k] << 5));
        #pragma unroll
        for (int k = 0; k < 8; ++k) {
          a0 += bflo(vv[k].x); a1 += bfhi(vv[k].x);
          a2 += bflo(vv[k].y); a3 += bfhi(vv[k].y);
          a4 += bflo(vv[k].z); a5 += bfhi(vv[k].z);
          a6 += bflo(vv[k].w); a7 += bfhi(vv[k].w);
        }
      }
    }

    if (valid) {
      const float4 b0 = *(const float4*)(bias + sl * 32 + cl * 8);
      const float4 b1 = *(const float4*)(bias + sl * 32 + cl * 8 + 4);
      f32x4 o0, o1;
      o0.x = fmaxf(fmaf(a0, dd, b0.x), 0.f);
      o0.y = fmaxf(fmaf(a1, dd, b0.y), 0.f);
      o0.z = fmaxf(fmaf(a2, dd, b0.z), 0.f);
      o0.w = fmaxf(fmaf(a3, dd, b0.w), 0.f);
      o1.x = fmaxf(fmaf(a4, dd, b1.x), 0.f);
      o1.y = fmaxf(fmaf(a5, dd, b1.y), 0.f);
      o1.z = fmaxf(fmaf(a6, dd, b1.z), 0.f);
      o1.w = fmaxf(fmaf(a7, dd, b1.w), 0.f);
      float* op = out + (size_t)node * 256 + sl * 32 + cl * 8;
      // NT store: 51 MB output written once; keep xwp slices in L2
      __builtin_nontemporal_store(o0, (f32x4*)op);
      __builtin_nontemporal_store(o1, (f32x4*)(op + 4));
    }
  }
}

// ---------------- launch ----------------

extern "C" void kernel_launch(void* const* d_in, const int* in_sizes, int n_in,
                              void* d_out, int out_size, void* d_ws, size_t ws_size,
                              hipStream_t stream) {
  const float* x  = (const float*)d_in[0];   // [n, 256]
  const int*   ei = (const int*)d_in[1];     // [2, E]
  const float* W  = (const float*)d_in[2];   // [256, 256]
  const float* b  = (const float*)d_in[3];   // [256]

  const int n = in_sizes[0] / FEATS;         // 50000
  const int E = in_sizes[1] / 2;             // 1,600,000
  const int* src = ei;
  const int* dst = ei + E;
  const int nbuck = (n + 255) >> 8;          // 196
  const int npad = n + 1;                    // +1 sentinel zero row per slice

  // workspace layout (bytes); real footprint ~37.4 MB
  char* ws = (char*)d_ws;
  size_t o0 = 0;
  unsigned short* xwp   = (unsigned short*)(ws + o0); o0 += (size_t)npad * 512;  // 8 slices x npad x 64 B
  unsigned short* Wt    = (unsigned short*)(ws + o0); o0 += 131072;
  float*          dinv  = (float*)(ws + o0);          o0 += 200064;
  int*            row_ptr = (int*)(ws + o0);          o0 += 200064;
  unsigned short* csr16 = (unsigned short*)(ws + o0); o0 += 3200000;
  int*            gcursor = (int*)(ws + o0);          o0 += 1024;
  int*            bbase   = (int*)(ws + o0);          o0 += 1024;
  unsigned*       temp    = (unsigned*)(ws + o0);     o0 += (size_t)nbuck * BCAP * 4;

  hipLaunchKernelGGL(init_misc, dim3(1), dim3(512), 0, stream, gcursor, nbuck, (int*)xwp, npad, n);
  hipLaunchKernelGGL(wt_build, dim3(256), dim3(256), 0, stream, W, Wt);

  const int g_p1 = (E + 4095) / 4096;  // 391
  hipLaunchKernelGGL(pass1_bin, dim3(g_p1), dim3(1024), 0, stream, src, dst, E, nbuck, gcursor, temp);
  hipLaunchKernelGGL(scan_buckets, dim3(1), dim3(256), 0, stream, gcursor, bbase, row_ptr, nbuck, n);
  hipLaunchKernelGGL(pass2_csr, dim3(nbuck), dim3(1024), 0, stream, temp, gcursor, bbase,
                     csr16, row_ptr, dinv, n);

  hipLaunchKernelGGL(gemm_mfma, dim3((n + 63) / 64), dim3(256), 0, stream, x, Wt, dinv, xwp, n, npad);

  // single dispatch: 64 nodes/block, all 8 slices looped inside (self-phased)
  hipLaunchKernelGGL(aggregate, dim3((n + 63) / 64), dim3(256), 0, stream,
                     xwp, dinv, row_ptr, csr16, b, (float*)d_out, n, npad);
}